// Round 5
// baseline (262.129 us; speedup 1.0000x reference)
//
#include <hip/hip_runtime.h>
#include <stdint.h>
#include <stddef.h>

// ---------- types ----------
typedef __bf16 bf16;
typedef __bf16 bf16x8 __attribute__((ext_vector_type(8)));
typedef __bf16 bf16x4 __attribute__((ext_vector_type(4)));
typedef float  f32x4  __attribute__((ext_vector_type(4)));
typedef float  f32x16 __attribute__((ext_vector_type(16)));
typedef unsigned short ush;
typedef ush ush8 __attribute__((ext_vector_type(8)));
typedef unsigned int uint;

// ---------- problem sizes ----------
#define B_  4
#define S_  2048
#define E_  1024
#define H_  16
#define D_  64
#define M_  (B_*S_)      // 8192 rows
#define K_  E_           // 1024 reduction
// 0.125 (1/sqrt(D)) * log2(e): QKV epilogue folds this into Q -> softmax in exp2 domain
#define QSCALE 0.18033688011112042f

// ---------- helpers ----------
__device__ __forceinline__ void gload_lds16(const void* g, void* l) {
  __builtin_amdgcn_global_load_lds((const __attribute__((address_space(1))) void*)g,
                                   (__attribute__((address_space(3))) void*)l, 16, 0, 0);
}
__device__ __forceinline__ f32x4 mfma16(bf16x8 a, bf16x8 b, f32x4 c) {
  return __builtin_amdgcn_mfma_f32_16x16x32_bf16(a, b, c, 0, 0, 0);
}
__device__ __forceinline__ f32x16 mfma32(bf16x8 a, bf16x8 b, f32x16 c) {
  return __builtin_amdgcn_mfma_f32_32x32x16_bf16(a, b, c, 0, 0, 0);
}
__device__ __forceinline__ int swz4(int row, int ch) { return ch ^ ((row >> 1) & 3); }
__device__ __forceinline__ uint cvtpk(float lo, float hi) {
  uint r;
  asm("v_cvt_pk_bf16_f32 %0, %1, %2" : "=v"(r) : "v"(lo), "v"(hi));
  return r;
}

// ---------- prep kernels ----------
__global__ void cast_f32_bf16(const float* __restrict__ src, bf16* __restrict__ dst, int n4) {
  int idx = blockIdx.x * blockDim.x + threadIdx.x;
  int stride = gridDim.x * blockDim.x;
  for (int i = idx; i < n4; i += stride) {
    float4 v = ((const float4*)src)[i];
    union { bf16 b[4]; ushort4 u; } cv;
    cv.b[0] = (bf16)v.x; cv.b[1] = (bf16)v.y; cv.b[2] = (bf16)v.z; cv.b[3] = (bf16)v.w;
    ((ushort4*)dst)[i] = cv.u;
  }
}

// pack Wq|Wk|Wv [H,E,D] -> Wp[n][e], n = which*1024 + h*64 + d. LDS-tiled transpose.
__global__ void pack_w_t(const float* __restrict__ Wq, const float* __restrict__ Wk,
                         const float* __restrict__ Wv, bf16* __restrict__ Wp) {
  __shared__ float t[64][65];
  const int tid = threadIdx.x;
  const int wh = blockIdx.y;          // 0..47
  const int which = wh >> 4, h = wh & 15;
  const int e0 = blockIdx.x << 6;
  const float* src = (which == 0) ? Wq : (which == 1 ? Wk : Wv);
  src += (size_t)h * (E_ * D_);       // [E][D] for this head
  #pragma unroll
  for (int i = 0; i < 4; ++i) {
    int fi = tid + 256 * i;
    int e = fi >> 4, c = fi & 15;
    float4 v = *(const float4*)(src + (size_t)(e0 + e) * D_ + c * 4);
    t[c * 4 + 0][e] = v.x; t[c * 4 + 1][e] = v.y;
    t[c * 4 + 2][e] = v.z; t[c * 4 + 3][e] = v.w;
  }
  __syncthreads();
  #pragma unroll
  for (int i = 0; i < 2; ++i) {
    int cid = tid + 256 * i;
    int d = cid >> 3, cc = cid & 7;
    ush8 o;
    #pragma unroll
    for (int j = 0; j < 8; ++j) {
      union { bf16 b; ush u; } cv; cv.b = (bf16)t[d][cc * 8 + j]; o[j] = cv.u;
    }
    *(ush8*)(Wp + ((size_t)which * 1024 + h * 64 + d) * K_ + e0 + cc * 8) = o;
  }
}

// ---------- GEMM: C[M][N] = A[M][K] * Bm[N][K]^T ----------
template <int MODE>
__launch_bounds__(256, 2)
__global__ void gemm_kernel(const bf16* __restrict__ A, const bf16* __restrict__ Bm,
                            int Ntot,
                            const float* __restrict__ bias0, const float* __restrict__ bias1,
                            const float* __restrict__ bias2,
                            bf16* __restrict__ Qo, bf16* __restrict__ Ko, bf16* __restrict__ Vo,
                            float* __restrict__ Fo) {
  __shared__ __align__(16) bf16 lds_a[2][128 * 32];
  __shared__ __align__(16) bf16 lds_b[2][128 * 32];
  const int tid = threadIdx.x;
  const int lane = tid & 63;
  const int w = tid >> 6;
  const int wr = w >> 1, wc = w & 1;
  const int nblk = Ntot >> 7;
  const int mt = blockIdx.x / nblk, nt = blockIdx.x % nblk;
  const int m0 = mt << 7, n0 = nt << 7;

  f32x4 acc[4][4] = {};

  auto stage = [&](int buf, int kt) {
    #pragma unroll
    for (int i = 0; i < 2; ++i) {
      int cb = (w * 2 + i) * 64;
      int cid = cb + lane;
      int row = cid >> 2, cir = cid & 3;
      int lch = swz4(row, cir);
      const bf16* ga = A  + (size_t)(m0 + row) * K_ + kt * 32 + lch * 8;
      const bf16* gb = Bm + (size_t)(n0 + row) * K_ + kt * 32 + lch * 8;
      gload_lds16(ga, &lds_a[buf][cb * 8]);
      gload_lds16(gb, &lds_b[buf][cb * 8]);
    }
  };

  const int NT = K_ / 32;
  stage(0, 0);
  for (int kt = 0; kt < NT; ++kt) {
    if (kt + 1 < NT) stage((kt + 1) & 1, kt + 1);
    __syncthreads();
    const bf16x8* pa = (const bf16x8*)&lds_a[kt & 1][0];
    const bf16x8* pb = (const bf16x8*)&lds_b[kt & 1][0];
    bf16x8 af[4], bfr[4];
    #pragma unroll
    for (int mb = 0; mb < 4; ++mb) {
      int row = wr * 64 + mb * 16 + (lane & 15);
      af[mb] = pa[row * 4 + swz4(row, lane >> 4)];
    }
    #pragma unroll
    for (int nb = 0; nb < 4; ++nb) {
      int row = wc * 64 + nb * 16 + (lane & 15);
      bfr[nb] = pb[row * 4 + swz4(row, lane >> 4)];
    }
    #pragma unroll
    for (int mb = 0; mb < 4; ++mb)
      #pragma unroll
      for (int nb = 0; nb < 4; ++nb)
        acc[mb][nb] = mfma16(af[mb], bfr[nb], acc[mb][nb]);
    __syncthreads();
  }

  #pragma unroll
  for (int mb = 0; mb < 4; ++mb) {
    #pragma unroll
    for (int nb = 0; nb < 4; ++nb) {
      #pragma unroll
      for (int r = 0; r < 4; ++r) {
        int mi = m0 + wr * 64 + mb * 16 + (lane >> 4) * 4 + r;
        int ni = n0 + wc * 64 + nb * 16 + (lane & 15);
        float v = acc[mb][nb][r];
        if (MODE == 0) {
          int which = ni >> 10;
          int col = ni & 1023;
          const float* bp = (which == 0) ? bias0 : (which == 1 ? bias1 : bias2);
          v += bp[col];
          if (which == 0) v *= QSCALE;   // fold 1/sqrt(D)*log2e into Q
          int h = col >> 6, d = col & 63;
          int b = mi >> 11, s = mi & 2047;
          bf16* dst = (which == 0) ? Qo : (which == 1 ? Ko : Vo);
          dst[(((size_t)(b * H_ + h)) * S_ + s) * D_ + d] = (bf16)v;
        } else {
          Fo[(size_t)mi * E_ + ni] = v + bias0[ni];
        }
      }
    }
  }
}

// ---------- V transpose: V[B,H,S,D] -> Vt[B,H,D,S] ----------
__global__ void transpose_v(const bf16* __restrict__ V, bf16* __restrict__ Vt) {
  __shared__ ush t[64 * 65];
  const int bh = blockIdx.y;
  const int s0 = blockIdx.x * 64;
  const int tid = threadIdx.x;
  #pragma unroll
  for (int i = 0; i < 2; ++i) {
    int cid = tid + 256 * i;
    int r = cid >> 3, c = cid & 7;
    ush8 val = *(const ush8*)(V + ((size_t)bh * S_ + s0 + r) * D_ + c * 8);
    #pragma unroll
    for (int j = 0; j < 8; ++j) t[(c * 8 + j) * 65 + r] = val[j];
  }
  __syncthreads();
  #pragma unroll
  for (int i = 0; i < 2; ++i) {
    int cid = tid + 256 * i;
    int d = cid >> 3, sc = cid & 7;
    ush8 o;
    #pragma unroll
    for (int j = 0; j < 8; ++j) o[j] = t[d * 65 + sc * 8 + j];
    *(ush8*)(Vt + ((size_t)bh * D_ + d) * S_ + s0 + sc * 8) = o;
  }
}

// ---------- flash attention (causal): 1-wave blocks, zero LDS, zero barriers ----------
// S^T = mfma(K, Q): lane owns q = ln; kv regs crow(r,hi)=(r&3)+8*(r>>2)+4*hi.
// O^T = mfma(Vt, P^T): col = q = ln -> softmax state fully lane-local.
// K/V fragments loaded directly from global (L2-resident per XCD); each wave's
// fragment reads cover each K/V tile byte exactly once -> LDS staging buys nothing.
struct QTile {
  bf16x8 qf[4];
  f32x16 oacc[2];
  float m, l;
};

__device__ __forceinline__ void init_q(QTile& S, const bf16* qrow, int hi) {
  #pragma unroll
  for (int kc = 0; kc < 4; ++kc)
    S.qf[kc] = *(const bf16x8*)(qrow + (2 * kc + hi) * 8);
  #pragma unroll
  for (int r = 0; r < 16; ++r) { S.oacc[0][r] = 0.f; S.oacc[1][r] = 0.f; }
  S.m = -1e30f; S.l = 0.f;
}

__device__ __forceinline__ void tile_step_g(QTile& S, const bf16* __restrict__ Kb,
                                            const bf16* __restrict__ Vb,
                                            int kv0, int qu, int qg_, int hi, int ln) {
  // ---- K fragments straight from global ----
  const bf16* kr0 = Kb + (size_t)(kv0 + ln) * D_;
  const bf16* kr1 = Kb + (size_t)(kv0 + 32 + ln) * D_;
  bf16x8 k0[4], k1[4];
  #pragma unroll
  for (int kc = 0; kc < 4; ++kc) {
    k0[kc] = *(const bf16x8*)(kr0 + (2 * kc + hi) * 8);
    k1[kc] = *(const bf16x8*)(kr1 + (2 * kc + hi) * 8);
  }
  // ---- V fragments (independent loads; latency hides under QK^T + softmax) ----
  bf16x8 vf[2][4];
  #pragma unroll
  for (int dm = 0; dm < 2; ++dm) {
    const bf16* vr = Vb + (size_t)(dm * 32 + ln) * S_ + kv0;
    #pragma unroll
    for (int ks = 0; ks < 4; ++ks)
      vf[dm][ks] = *(const bf16x8*)(vr + (2 * ks + hi) * 8);
  }
  // ---- QK^T ----
  f32x16 s0 = {}, s1 = {};
  #pragma unroll
  for (int kc = 0; kc < 4; ++kc) {
    s0 = mfma32(k0[kc], S.qf[kc], s0);
    s1 = mfma32(k1[kc], S.qf[kc], s1);
  }
  // causal mask (only the diagonal-touching tile)
  if (kv0 + 63 > qu) {
    #pragma unroll
    for (int r = 0; r < 16; ++r) {
      int crow = (r & 3) + 8 * (r >> 2) + 4 * hi;
      if (kv0 + crow > qg_)      s0[r] = -1e30f;
      if (kv0 + 32 + crow > qg_) s1[r] = -1e30f;
    }
  }
  // ---- online softmax, lane-local (exp2 domain) ----
  float mt_ = s0[0];
  #pragma unroll
  for (int r = 1; r < 16; ++r) mt_ = fmaxf(mt_, s0[r]);
  #pragma unroll
  for (int r = 0; r < 16; ++r) mt_ = fmaxf(mt_, s1[r]);
  mt_ = fmaxf(mt_, __shfl_xor(mt_, 32, 64));
  bool resc = mt_ > S.m + 8.f;          // defer-max (T13)
  float mnew = resc ? mt_ : S.m;
  float alpha = resc ? exp2f(S.m - mnew) : 1.f;
  S.m = mnew;
  float rs = 0.f;
  #pragma unroll
  for (int r = 0; r < 16; ++r) { float p = exp2f(s0[r] - mnew); s0[r] = p; rs += p; }
  #pragma unroll
  for (int r = 0; r < 16; ++r) { float p = exp2f(s1[r] - mnew); s1[r] = p; rs += p; }
  rs += __shfl_xor(rs, 32, 64);
  S.l = S.l * alpha + rs;
  if (__any(resc)) {
    #pragma unroll
    for (int r = 0; r < 16; ++r) { S.oacc[0][r] *= alpha; S.oacc[1][r] *= alpha; }
  }
  // ---- pack P -> PV B-fragments (cvt_pk + permlane32_swap, T12) ----
  bf16x8 pf[4];
  #pragma unroll
  for (int mtl = 0; mtl < 2; ++mtl) {
    #pragma unroll
    for (int c = 0; c < 2; ++c) {
      const f32x16& p = mtl ? s1 : s0;
      uint wa = cvtpk(p[8 * c + 0], p[8 * c + 1]);
      uint wb = cvtpk(p[8 * c + 2], p[8 * c + 3]);
      uint wcx = cvtpk(p[8 * c + 4], p[8 * c + 5]);
      uint wd = cvtpk(p[8 * c + 6], p[8 * c + 7]);
      asm("v_permlane32_swap_b32 %0, %1" : "+v"(wa), "+v"(wcx));
      asm("v_permlane32_swap_b32 %0, %1" : "+v"(wb), "+v"(wd));
      union { uint u[4]; bf16x8 v; } cvt;
      cvt.u[0] = wa; cvt.u[1] = wb; cvt.u[2] = wcx; cvt.u[3] = wd;
      pf[mtl * 2 + c] = cvt.v;
    }
  }
  // ---- O^T += Vt * P^T ----
  #pragma unroll
  for (int dm = 0; dm < 2; ++dm)
    #pragma unroll
    for (int ks = 0; ks < 4; ++ks)
      S.oacc[dm] = mfma32(vf[dm][ks], pf[ks], S.oacc[dm]);
}

__device__ __forceinline__ void store_o(const QTile& S, bf16* orow, int hi) {
  float rinv = 1.f / S.l;
  #pragma unroll
  for (int dm = 0; dm < 2; ++dm) {
    #pragma unroll
    for (int g = 0; g < 4; ++g) {
      bf16x4 st;
      #pragma unroll
      for (int i = 0; i < 4; ++i) st[i] = (bf16)(S.oacc[dm][4 * g + i] * rinv);
      *(bf16x4*)(orow + dm * 32 + g * 8 + hi * 4) = st;
    }
  }
}

// grid: 2048 x 64 threads. Block = q-units {p, 63-p} (32 rows each), processed
// sequentially -> uniform 33 kv-tile steps/block. bh's 32 blocks share an XCD.
__launch_bounds__(64, 3)
__global__ void attn_kernel(const bf16* __restrict__ Q, const bf16* __restrict__ K,
                            const bf16* __restrict__ Vt, bf16* __restrict__ Oc) {
  const int tid = threadIdx.x, hi = tid >> 5, ln = tid & 31;
  const int i = blockIdx.x;
  const int bh = (i & 7) | ((i >> 8) << 3);
  const int p = (i >> 3) & 31;
  const bf16* Kb = K  + (size_t)bh * S_ * D_;
  const bf16* Vb = Vt + (size_t)bh * D_ * S_;
  const int b = bh >> 4, h = bh & 15;

  for (int half = 0; half < 2; ++half) {
    const int u = half ? (63 - p) : p;
    const int qu = u * 32;
    QTile S;
    init_q(S, Q + ((size_t)bh * S_ + qu + ln) * D_, hi);
    const int ntl = (u >> 1) + 1;
    for (int t = 0; t < ntl; ++t)
      tile_step_g(S, Kb, Vb, t * 64, qu, qu + ln, hi, ln);
    store_o(S, Oc + ((size_t)(b * S_ + qu + ln)) * E_ + h * D_, hi);
  }
}

// ---------- launcher ----------
extern "C" void kernel_launch(void* const* d_in, const int* in_sizes, int n_in,
                              void* d_out, int out_size, void* d_ws, size_t ws_size,
                              hipStream_t stream) {
  const float* x  = (const float*)d_in[0];
  const float* Wq = (const float*)d_in[1];
  const float* bq = (const float*)d_in[2];
  const float* Wk = (const float*)d_in[3];
  const float* bk = (const float*)d_in[4];
  const float* Wv = (const float*)d_in[5];
  const float* bv = (const float*)d_in[6];
  const float* Wo = (const float*)d_in[7];
  const float* bo = (const float*)d_in[8];
  float* out = (float*)d_out;

  uint8_t* ws = (uint8_t*)d_ws;
  bf16* Xbf   = (bf16*)(ws + 0);           // [M][K]; later reused as concat
  bf16* Wpack = (bf16*)(ws + 16777216);    // [3072][1024]
  bf16* Wot   = (bf16*)(ws + 23068672);    // [1024][1024]
  bf16* Qb    = (bf16*)(ws + 25165824);    // [B,H,S,D] (pre-scaled)
  bf16* Kb    = (bf16*)(ws + 41943040);
  bf16* Vb    = (bf16*)(ws + 58720256);
  bf16* Vtb   = (bf16*)(ws + 75497472);    // [B,H,D,S]
  bf16* Cc    = Xbf;

  cast_f32_bf16<<<2048, 256, 0, stream>>>(x,  Xbf, (M_ * K_) / 4);
  cast_f32_bf16<<<1024, 256, 0, stream>>>(Wo, Wot, (E_ * E_) / 4);
  pack_w_t<<<dim3(16, 48), 256, 0, stream>>>(Wq, Wk, Wv, Wpack);

  gemm_kernel<0><<<dim3(64 * 24), 256, 0, stream>>>(Xbf, Wpack, 3072, bq, bk, bv,
                                                    Qb, Kb, Vb, nullptr);
  transpose_v<<<dim3(S_ / 64, B_ * H_), 256, 0, stream>>>(Vb, Vtb);

  attn_kernel<<<2048, 64, 0, stream>>>(Qb, Kb, Vtb, Cc);

  gemm_kernel<1><<<dim3(64 * 8), 256, 0, stream>>>(Cc, Wot, 1024, bo, nullptr, nullptr,
                                                   nullptr, nullptr, nullptr, out);
}

// Round 6
// 261.891 us; speedup vs baseline: 1.0009x; 1.0009x over previous
//
#include <hip/hip_runtime.h>
#include <stdint.h>
#include <stddef.h>

// ---------- types ----------
typedef __bf16 bf16;
typedef __bf16 bf16x8 __attribute__((ext_vector_type(8)));
typedef __bf16 bf16x4 __attribute__((ext_vector_type(4)));
typedef float  f32x4  __attribute__((ext_vector_type(4)));
typedef float  f32x16 __attribute__((ext_vector_type(16)));
typedef unsigned short ush;
typedef ush ush8 __attribute__((ext_vector_type(8)));
typedef unsigned int uint;

// ---------- problem sizes ----------
#define B_  4
#define S_  2048
#define E_  1024
#define H_  16
#define D_  64
#define M_  (B_*S_)      // 8192 rows
#define K_  E_           // 1024 reduction
// 0.125 (1/sqrt(D)) * log2(e): QKV epilogue folds this into Q -> softmax in exp2 domain
#define QSCALE 0.18033688011112042f

// ---------- helpers ----------
__device__ __forceinline__ void gload_lds16(const void* g, void* l) {
  __builtin_amdgcn_global_load_lds((const __attribute__((address_space(1))) void*)g,
                                   (__attribute__((address_space(3))) void*)l, 16, 0, 0);
}
__device__ __forceinline__ f32x4 mfma16(bf16x8 a, bf16x8 b, f32x4 c) {
  return __builtin_amdgcn_mfma_f32_16x16x32_bf16(a, b, c, 0, 0, 0);
}
__device__ __forceinline__ f32x16 mfma32(bf16x8 a, bf16x8 b, f32x16 c) {
  return __builtin_amdgcn_mfma_f32_32x32x16_bf16(a, b, c, 0, 0, 0);
}
__device__ __forceinline__ int swz4(int row, int ch) { return ch ^ ((row >> 1) & 3); }
__device__ __forceinline__ uint cvtpk(float lo, float hi) {
  uint r;
  asm("v_cvt_pk_bf16_f32 %0, %1, %2" : "=v"(r) : "v"(lo), "v"(hi));
  return r;
}

// ---------- prep kernels ----------
__global__ void cast_f32_bf16(const float* __restrict__ src, bf16* __restrict__ dst, int n4) {
  int idx = blockIdx.x * blockDim.x + threadIdx.x;
  int stride = gridDim.x * blockDim.x;
  for (int i = idx; i < n4; i += stride) {
    float4 v = ((const float4*)src)[i];
    union { bf16 b[4]; ushort4 u; } cv;
    cv.b[0] = (bf16)v.x; cv.b[1] = (bf16)v.y; cv.b[2] = (bf16)v.z; cv.b[3] = (bf16)v.w;
    ((ushort4*)dst)[i] = cv.u;
  }
}

// pack Wq|Wk|Wv [H,E,D] -> Wp[n][e], n = which*1024 + h*64 + d. LDS-tiled transpose.
__global__ void pack_w_t(const float* __restrict__ Wq, const float* __restrict__ Wk,
                         const float* __restrict__ Wv, bf16* __restrict__ Wp) {
  __shared__ float t[64][65];
  const int tid = threadIdx.x;
  const int wh = blockIdx.y;          // 0..47
  const int which = wh >> 4, h = wh & 15;
  const int e0 = blockIdx.x << 6;
  const float* src = (which == 0) ? Wq : (which == 1 ? Wk : Wv);
  src += (size_t)h * (E_ * D_);       // [E][D] for this head
  #pragma unroll
  for (int i = 0; i < 4; ++i) {
    int fi = tid + 256 * i;
    int e = fi >> 4, c = fi & 15;
    float4 v = *(const float4*)(src + (size_t)(e0 + e) * D_ + c * 4);
    t[c * 4 + 0][e] = v.x; t[c * 4 + 1][e] = v.y;
    t[c * 4 + 2][e] = v.z; t[c * 4 + 3][e] = v.w;
  }
  __syncthreads();
  #pragma unroll
  for (int i = 0; i < 2; ++i) {
    int cid = tid + 256 * i;
    int d = cid >> 3, cc = cid & 7;
    ush8 o;
    #pragma unroll
    for (int j = 0; j < 8; ++j) {
      union { bf16 b; ush u; } cv; cv.b = (bf16)t[d][cc * 8 + j]; o[j] = cv.u;
    }
    *(ush8*)(Wp + ((size_t)which * 1024 + h * 64 + d) * K_ + e0 + cc * 8) = o;
  }
}

// ---------- GEMM: C[M][N] = A[M][K] * Bm[N][K]^T ----------
template <int MODE>
__launch_bounds__(256, 2)
__global__ void gemm_kernel(const bf16* __restrict__ A, const bf16* __restrict__ Bm,
                            int Ntot,
                            const float* __restrict__ bias0, const float* __restrict__ bias1,
                            const float* __restrict__ bias2,
                            bf16* __restrict__ Qo, bf16* __restrict__ Ko, bf16* __restrict__ Vo,
                            float* __restrict__ Fo) {
  __shared__ __align__(16) bf16 lds_a[2][128 * 32];
  __shared__ __align__(16) bf16 lds_b[2][128 * 32];
  const int tid = threadIdx.x;
  const int lane = tid & 63;
  const int w = tid >> 6;
  const int wr = w >> 1, wc = w & 1;
  const int nblk = Ntot >> 7;
  const int mt = blockIdx.x / nblk, nt = blockIdx.x % nblk;
  const int m0 = mt << 7, n0 = nt << 7;

  f32x4 acc[4][4] = {};

  auto stage = [&](int buf, int kt) {
    #pragma unroll
    for (int i = 0; i < 2; ++i) {
      int cb = (w * 2 + i) * 64;
      int cid = cb + lane;
      int row = cid >> 2, cir = cid & 3;
      int lch = swz4(row, cir);
      const bf16* ga = A  + (size_t)(m0 + row) * K_ + kt * 32 + lch * 8;
      const bf16* gb = Bm + (size_t)(n0 + row) * K_ + kt * 32 + lch * 8;
      gload_lds16(ga, &lds_a[buf][cb * 8]);
      gload_lds16(gb, &lds_b[buf][cb * 8]);
    }
  };

  const int NT = K_ / 32;
  stage(0, 0);
  for (int kt = 0; kt < NT; ++kt) {
    if (kt + 1 < NT) stage((kt + 1) & 1, kt + 1);
    __syncthreads();
    const bf16x8* pa = (const bf16x8*)&lds_a[kt & 1][0];
    const bf16x8* pb = (const bf16x8*)&lds_b[kt & 1][0];
    bf16x8 af[4], bfr[4];
    #pragma unroll
    for (int mb = 0; mb < 4; ++mb) {
      int row = wr * 64 + mb * 16 + (lane & 15);
      af[mb] = pa[row * 4 + swz4(row, lane >> 4)];
    }
    #pragma unroll
    for (int nb = 0; nb < 4; ++nb) {
      int row = wc * 64 + nb * 16 + (lane & 15);
      bfr[nb] = pb[row * 4 + swz4(row, lane >> 4)];
    }
    #pragma unroll
    for (int mb = 0; mb < 4; ++mb)
      #pragma unroll
      for (int nb = 0; nb < 4; ++nb)
        acc[mb][nb] = mfma16(af[mb], bfr[nb], acc[mb][nb]);
    __syncthreads();
  }

  #pragma unroll
  for (int mb = 0; mb < 4; ++mb) {
    #pragma unroll
    for (int nb = 0; nb < 4; ++nb) {
      #pragma unroll
      for (int r = 0; r < 4; ++r) {
        int mi = m0 + wr * 64 + mb * 16 + (lane >> 4) * 4 + r;
        int ni = n0 + wc * 64 + nb * 16 + (lane & 15);
        float v = acc[mb][nb][r];
        if (MODE == 0) {
          int which = ni >> 10;
          int col = ni & 1023;
          const float* bp = (which == 0) ? bias0 : (which == 1 ? bias1 : bias2);
          v += bp[col];
          if (which == 0) v *= QSCALE;   // fold 1/sqrt(D)*log2e into Q
          int h = col >> 6, d = col & 63;
          int b = mi >> 11, s = mi & 2047;
          bf16* dst = (which == 0) ? Qo : (which == 1 ? Ko : Vo);
          dst[(((size_t)(b * H_ + h)) * S_ + s) * D_ + d] = (bf16)v;
        } else {
          Fo[(size_t)mi * E_ + ni] = v + bias0[ni];
        }
      }
    }
  }
}

// ---------- V transpose: V[B,H,S,D] -> Vt[B,H,D,S] ----------
__global__ void transpose_v(const bf16* __restrict__ V, bf16* __restrict__ Vt) {
  __shared__ ush t[64 * 65];
  const int bh = blockIdx.y;
  const int s0 = blockIdx.x * 64;
  const int tid = threadIdx.x;
  #pragma unroll
  for (int i = 0; i < 2; ++i) {
    int cid = tid + 256 * i;
    int r = cid >> 3, c = cid & 7;
    ush8 val = *(const ush8*)(V + ((size_t)bh * S_ + s0 + r) * D_ + c * 8);
    #pragma unroll
    for (int j = 0; j < 8; ++j) t[(c * 8 + j) * 65 + r] = val[j];
  }
  __syncthreads();
  #pragma unroll
  for (int i = 0; i < 2; ++i) {
    int cid = tid + 256 * i;
    int d = cid >> 3, sc = cid & 7;
    ush8 o;
    #pragma unroll
    for (int j = 0; j < 8; ++j) o[j] = t[d * 65 + sc * 8 + j];
    *(ush8*)(Vt + ((size_t)bh * D_ + d) * S_ + s0 + sc * 8) = o;
  }
}

// ---------- flash attention (causal): kv-parity split, 2-wave blocks ----------
// Block = one 32-row q-unit; wave w processes kv tiles t == w (mod 2), each with
// its own online-softmax state; single LDS merge at the end. No barriers in loop.
// S^T = mfma(K, Q): lane owns q = ln; kv regs crow(r,hi)=(r&3)+8*(r>>2)+4*hi.
// O^T = mfma(Vt, P^T): col = q = ln -> softmax state fully lane-local.
struct QTile {
  bf16x8 qf[4];
  f32x16 oacc[2];
  float m, l;
};

__device__ __forceinline__ void init_q(QTile& S, const bf16* qrow, int hi) {
  #pragma unroll
  for (int kc = 0; kc < 4; ++kc)
    S.qf[kc] = *(const bf16x8*)(qrow + (2 * kc + hi) * 8);
  #pragma unroll
  for (int r = 0; r < 16; ++r) { S.oacc[0][r] = 0.f; S.oacc[1][r] = 0.f; }
  S.m = -1e30f; S.l = 0.f;
}

__device__ __forceinline__ void tile_step_g(QTile& S, const bf16* __restrict__ Kb,
                                            const bf16* __restrict__ Vb,
                                            int kv0, int qu, int qg_, int hi, int ln) {
  // ---- K fragments straight from global (L2-resident) ----
  const bf16* kr0 = Kb + (size_t)(kv0 + ln) * D_;
  const bf16* kr1 = Kb + (size_t)(kv0 + 32 + ln) * D_;
  bf16x8 k0[4], k1[4];
  #pragma unroll
  for (int kc = 0; kc < 4; ++kc) {
    k0[kc] = *(const bf16x8*)(kr0 + (2 * kc + hi) * 8);
    k1[kc] = *(const bf16x8*)(kr1 + (2 * kc + hi) * 8);
  }
  // ---- QK^T ----
  f32x16 s0 = {}, s1 = {};
  __builtin_amdgcn_s_setprio(1);
  #pragma unroll
  for (int kc = 0; kc < 4; ++kc) {
    s0 = mfma32(k0[kc], S.qf[kc], s0);
    s1 = mfma32(k1[kc], S.qf[kc], s1);
  }
  __builtin_amdgcn_s_setprio(0);
  // ---- V fragments (issue early; latency hides under softmax) ----
  bf16x8 vf[2][4];
  #pragma unroll
  for (int dm = 0; dm < 2; ++dm) {
    const bf16* vr = Vb + (size_t)(dm * 32 + ln) * S_ + kv0;
    #pragma unroll
    for (int ks = 0; ks < 4; ++ks)
      vf[dm][ks] = *(const bf16x8*)(vr + (2 * ks + hi) * 8);
  }
  // causal mask (only the diagonal-touching tile)
  if (kv0 + 63 > qu) {
    #pragma unroll
    for (int r = 0; r < 16; ++r) {
      int crow = (r & 3) + 8 * (r >> 2) + 4 * hi;
      if (kv0 + crow > qg_)      s0[r] = -1e30f;
      if (kv0 + 32 + crow > qg_) s1[r] = -1e30f;
    }
  }
  // ---- online softmax, lane-local (exp2 domain) ----
  float mt_ = s0[0];
  #pragma unroll
  for (int r = 1; r < 16; ++r) mt_ = fmaxf(mt_, s0[r]);
  #pragma unroll
  for (int r = 0; r < 16; ++r) mt_ = fmaxf(mt_, s1[r]);
  mt_ = fmaxf(mt_, __shfl_xor(mt_, 32, 64));
  bool resc = mt_ > S.m + 8.f;          // defer-max (T13)
  float mnew = resc ? mt_ : S.m;
  float alpha = resc ? exp2f(S.m - mnew) : 1.f;
  S.m = mnew;
  float rs = 0.f;
  #pragma unroll
  for (int r = 0; r < 16; ++r) { float p = exp2f(s0[r] - mnew); s0[r] = p; rs += p; }
  #pragma unroll
  for (int r = 0; r < 16; ++r) { float p = exp2f(s1[r] - mnew); s1[r] = p; rs += p; }
  rs += __shfl_xor(rs, 32, 64);
  S.l = S.l * alpha + rs;
  if (__any(resc)) {
    #pragma unroll
    for (int r = 0; r < 16; ++r) { S.oacc[0][r] *= alpha; S.oacc[1][r] *= alpha; }
  }
  // ---- pack P -> PV B-fragments (cvt_pk + permlane32_swap, T12) ----
  bf16x8 pf[4];
  #pragma unroll
  for (int mtl = 0; mtl < 2; ++mtl) {
    #pragma unroll
    for (int c = 0; c < 2; ++c) {
      const f32x16& p = mtl ? s1 : s0;
      uint wa = cvtpk(p[8 * c + 0], p[8 * c + 1]);
      uint wb = cvtpk(p[8 * c + 2], p[8 * c + 3]);
      uint wcx = cvtpk(p[8 * c + 4], p[8 * c + 5]);
      uint wd = cvtpk(p[8 * c + 6], p[8 * c + 7]);
      asm("v_permlane32_swap_b32 %0, %1" : "+v"(wa), "+v"(wcx));
      asm("v_permlane32_swap_b32 %0, %1" : "+v"(wb), "+v"(wd));
      union { uint u[4]; bf16x8 v; } cvt;
      cvt.u[0] = wa; cvt.u[1] = wb; cvt.u[2] = wcx; cvt.u[3] = wd;
      pf[mtl * 2 + c] = cvt.v;
    }
  }
  // ---- O^T += Vt * P^T ----
  __builtin_amdgcn_s_setprio(1);
  #pragma unroll
  for (int dm = 0; dm < 2; ++dm)
    #pragma unroll
    for (int ks = 0; ks < 4; ++ks)
      S.oacc[dm] = mfma32(vf[dm][ks], pf[ks], S.oacc[dm]);
  __builtin_amdgcn_s_setprio(0);
}

__device__ __forceinline__ void store_o(const QTile& S, bf16* orow, int hi) {
  float rinv = 1.f / S.l;
  #pragma unroll
  for (int dm = 0; dm < 2; ++dm) {
    #pragma unroll
    for (int g = 0; g < 4; ++g) {
      bf16x4 st;
      #pragma unroll
      for (int i = 0; i < 4; ++i) st[i] = (bf16)(S.oacc[dm][4 * g + i] * rinv);
      *(bf16x4*)(orow + dm * 32 + g * 8 + hi * 4) = st;
    }
  }
}

// grid: 4096 x 128 threads. Block = q-unit u of bh; wave 0 even kv tiles, wave 1
// odd kv tiles; merge once via LDS. u descending (longest first) for backfill;
// bid&7 pins bh's blocks to one XCD for K/V L2 locality.
__launch_bounds__(128, 4)
__global__ void attn_kernel(const bf16* __restrict__ Q, const bf16* __restrict__ K,
                            const bf16* __restrict__ Vt, bf16* __restrict__ Oc) {
  __shared__ float obuf[32][64];      // wave1 O^T regs, [reg r][lane]
  __shared__ float mlbuf[2][64];
  const int tid = threadIdx.x, lane = tid & 63, w = tid >> 6;
  const int hi = lane >> 5, ln = lane & 31;
  const int bid = blockIdx.x;
  const int bh = (bid & 7) | (((bid >> 3) & 7) << 3);
  const int u  = 63 - (bid >> 6);
  const int qu = u * 32;
  const int qg = qu + ln;
  const int Tu = (u >> 1) + 1;
  const bf16* Kb = K  + (size_t)bh * (S_ * D_);
  const bf16* Vb = Vt + (size_t)bh * (D_ * S_);

  QTile S;
  init_q(S, Q + ((size_t)bh * S_ + qg) * D_, hi);
  for (int t = w; t < Tu; t += 2)
    tile_step_g(S, Kb, Vb, t * 64, qu, qg, hi, ln);

  if (w == 1) {
    mlbuf[0][lane] = S.m; mlbuf[1][lane] = S.l;
    #pragma unroll
    for (int dm = 0; dm < 2; ++dm)
      #pragma unroll
      for (int r = 0; r < 16; ++r)
        obuf[dm * 16 + r][lane] = S.oacc[dm][r];
  }
  __syncthreads();
  if (w == 0) {
    float mB = mlbuf[0][lane], lB = mlbuf[1][lane];
    float mN = fmaxf(S.m, mB);
    float aA = exp2f(S.m - mN), aB = exp2f(mB - mN);
    S.l = S.l * aA + lB * aB;
    #pragma unroll
    for (int dm = 0; dm < 2; ++dm)
      #pragma unroll
      for (int r = 0; r < 16; ++r)
        S.oacc[dm][r] = S.oacc[dm][r] * aA + obuf[dm * 16 + r][lane] * aB;
    const int b = bh >> 4, h = bh & 15;
    store_o(S, Oc + ((size_t)(b * S_ + qg)) * E_ + h * D_, hi);
  }
}

// ---------- launcher ----------
extern "C" void kernel_launch(void* const* d_in, const int* in_sizes, int n_in,
                              void* d_out, int out_size, void* d_ws, size_t ws_size,
                              hipStream_t stream) {
  const float* x  = (const float*)d_in[0];
  const float* Wq = (const float*)d_in[1];
  const float* bq = (const float*)d_in[2];
  const float* Wk = (const float*)d_in[3];
  const float* bk = (const float*)d_in[4];
  const float* Wv = (const float*)d_in[5];
  const float* bv = (const float*)d_in[6];
  const float* Wo = (const float*)d_in[7];
  const float* bo = (const float*)d_in[8];
  float* out = (float*)d_out;

  uint8_t* ws = (uint8_t*)d_ws;
  bf16* Xbf   = (bf16*)(ws + 0);           // [M][K]; later reused as concat
  bf16* Wpack = (bf16*)(ws + 16777216);    // [3072][1024]
  bf16* Wot   = (bf16*)(ws + 23068672);    // [1024][1024]
  bf16* Qb    = (bf16*)(ws + 25165824);    // [B,H,S,D] (pre-scaled)
  bf16* Kb    = (bf16*)(ws + 41943040);
  bf16* Vb    = (bf16*)(ws + 58720256);
  bf16* Vtb   = (bf16*)(ws + 75497472);    // [B,H,D,S]
  bf16* Cc    = Xbf;

  cast_f32_bf16<<<2048, 256, 0, stream>>>(x,  Xbf, (M_ * K_) / 4);
  cast_f32_bf16<<<1024, 256, 0, stream>>>(Wo, Wot, (E_ * E_) / 4);
  pack_w_t<<<dim3(16, 48), 256, 0, stream>>>(Wq, Wk, Wv, Wpack);

  gemm_kernel<0><<<dim3(64 * 24), 256, 0, stream>>>(Xbf, Wpack, 3072, bq, bk, bv,
                                                    Qb, Kb, Vb, nullptr);
  transpose_v<<<dim3(S_ / 64, B_ * H_), 256, 0, stream>>>(Vb, Vtb);

  attn_kernel<<<4096, 128, 0, stream>>>(Qb, Kb, Vtb, Cc);

  gemm_kernel<1><<<dim3(64 * 8), 256, 0, stream>>>(Cc, Wot, 1024, bo, nullptr, nullptr,
                                                   nullptr, nullptr, nullptr, out);
}